// Round 4
// baseline (764.068 us; speedup 1.0000x reference)
//
#include <hip/hip_runtime.h>

// (B,T,C,H) = (8,2048,1024,16), D=64
#define Tdim 2048

typedef __attribute__((ext_vector_type(8))) short bf16x8;
typedef __attribute__((ext_vector_type(4))) float f32x4;
typedef __attribute__((ext_vector_type(4))) short short4v;

#define GLOBAL_U32(p) ((const __attribute__((address_space(1))) unsigned int*)(p))
#define LDS_U32(p)    ((__attribute__((address_space(3))) unsigned int*)(p))

__device__ __forceinline__ float phi_f(float x) {
    return x > 0.f ? (x + 1.f) : __expf(x);
}
// round-to-nearest-even fp32 -> bf16 (finite inputs only)
__device__ __forceinline__ short f2bf(float f) {
    unsigned u = __float_as_uint(f);
    u += 0x7fffu + ((u >> 16) & 1u);
    return (short)(u >> 16);
}
__device__ __forceinline__ float bf2f(short h) {
    return __uint_as_float(((unsigned)(unsigned short)h) << 16);
}

// ---------------------------------------------------------------------------
// Elementwise split: X fp32 -> (hi, lo) bf16.  n4 = n/4 float4 groups.
// ---------------------------------------------------------------------------
__global__ __launch_bounds__(256) void split_kernel(
    const float* __restrict__ X, short* __restrict__ Hi, short* __restrict__ Lo, int n4)
{
    const int i = blockIdx.x * 256 + threadIdx.x;
    if (i >= n4) return;
    const float4 v = ((const float4*)X)[i];
    short4v h, l;
    h.x = f2bf(v.x); l.x = f2bf(v.x - bf2f(h.x));
    h.y = f2bf(v.y); l.y = f2bf(v.y - bf2f(h.y));
    h.z = f2bf(v.z); l.z = f2bf(v.z - bf2f(h.z));
    h.w = f2bf(v.w); l.w = f2bf(v.w - bf2f(h.w));
    ((short4v*)Hi)[i] = h;
    ((short4v*)Lo)[i] = l;
}

// ---------------------------------------------------------------------------
// W[K,N] fp32 -> transposed split T[N,K] bf16 hi/lo. 32x32 tiles.
// ---------------------------------------------------------------------------
__global__ __launch_bounds__(256) void split_transpose_kernel(
    const float* __restrict__ W, int K, int N,
    short* __restrict__ Thi, short* __restrict__ Tlo)
{
    __shared__ float tile[32][33];
    const int n0 = blockIdx.x * 32, k0 = blockIdx.y * 32;
    const int tx = threadIdx.x & 31, ty = threadIdx.x >> 5;   // ty 0..7
#pragma unroll
    for (int r = 0; r < 32; r += 8)
        tile[ty + r][tx] = W[(size_t)(k0 + ty + r) * N + n0 + tx];
    __syncthreads();
#pragma unroll
    for (int r = 0; r < 32; r += 8) {
        const float v = tile[tx][ty + r];            // = W[k0+tx][n0+ty+r]
        const short h = f2bf(v);
        const short l = f2bf(v - bf2f(h));
        Thi[(size_t)(n0 + ty + r) * K + k0 + tx] = h;
        Tlo[(size_t)(n0 + ty + r) * K + k0 + tx] = l;
    }
}

// ---------------------------------------------------------------------------
// bf16x3 split-precision GEMM: C = (Ahi+Alo)[M,K] * (Bhi+Blo)^T[N,K] + bias
// (drops lo*lo). 128x128 tile, BK=32, 4 waves x (4x4 of 16x16x32 MFMA).
// Staging is in MFMA LANE ORDER: lane L fetches (row = L&15, kchunk = L>>4)
// of each 16-row tile, so every fragment read is tile_base + lane*16B
// (identity mapping -> conflict-free LDS).
// AMODE 0: A hi/lo in separate linear [M,lda] buffers.
// AMODE 1: A hi/lo head-packed in one buffer (row stride lda shorts; k ->
//          (k>>6)*128 + (k&63), lo at +64) — y written in place over qkv q-slice.
// ---------------------------------------------------------------------------
template<int AMODE>
__global__ __launch_bounds__(256) void gemm3_kernel(
    const short* __restrict__ Ahi, const short* __restrict__ Alo, int lda,
    const short* __restrict__ BThi, const short* __restrict__ BTlo,
    const float* __restrict__ bias, float* __restrict__ C,
    int K, int ldc)
{
    __shared__ short smem[16384];   // 4 arrays x 8 tiles x 512 shorts = 32 KiB
    const int tid = threadIdx.x;
    const int lane = tid & 63;
    const int wid = tid >> 6;       // wave 0..3
    const int bx = blockIdx.x, by = blockIdx.y;
    const int wm = wid >> 1, wn = wid & 1;

    // staging: wave w owns LDS array w (0:Ahi 1:Alo 2:BThi 3:BTlo)
    const short* gbase;
    int stride;
    size_t rowbase;
    if (wid < 2) { gbase = (wid == 0) ? Ahi : Alo; stride = lda; rowbase = (size_t)by * 128; }
    else         { gbase = (wid == 2) ? BThi : BTlo; stride = K; rowbase = (size_t)bx * 128; }
    // lane map: row = lane&15 within tile, k-subchunk = (lane>>4)*8 shorts
    const short* gptr = gbase + (rowbase + (lane & 15)) * (size_t)stride + (lane >> 4) * 8;
    short* lbase = smem + wid * 4096;   // wave-uniform LDS base (shorts)

    f32x4 acc[4][4];
#pragma unroll
    for (int i = 0; i < 4; ++i)
#pragma unroll
        for (int j = 0; j < 4; ++j) acc[i][j] = (f32x4){0.f, 0.f, 0.f, 0.f};

    const int fr = lane & 15, fq = lane >> 4;
    const int lslot = lane * 8;     // shorts: fragment slot within a tile

    for (int k0 = 0; k0 < K; k0 += 32) {
        int koff;
        if (AMODE == 1 && wid < 2)
            koff = ((k0 >> 6) << 7) + (k0 & 32) + (wid == 1 ? 64 : 0);
        else
            koff = k0;
#pragma unroll
        for (int c = 0; c < 8; ++c) {
            __builtin_amdgcn_global_load_lds(
                GLOBAL_U32(gptr + (size_t)(c * 16) * stride + koff),
                LDS_U32(lbase + c * 512), 16, 0, 0);
        }
        __syncthreads();

        bf16x8 ah[4], al[4], bh[4], bl[4];
#pragma unroll
        for (int i = 0; i < 4; ++i) {
            ah[i] = *(const bf16x8*)(smem + (wm * 4 + i) * 512 + lslot);
            al[i] = *(const bf16x8*)(smem + 4096 + (wm * 4 + i) * 512 + lslot);
            bh[i] = *(const bf16x8*)(smem + 8192 + (wn * 4 + i) * 512 + lslot);
            bl[i] = *(const bf16x8*)(smem + 12288 + (wn * 4 + i) * 512 + lslot);
        }
#pragma unroll
        for (int i = 0; i < 4; ++i)
#pragma unroll
            for (int j = 0; j < 4; ++j) {
                acc[i][j] = __builtin_amdgcn_mfma_f32_16x16x32_bf16(ah[i], bh[j], acc[i][j], 0, 0, 0);
                acc[i][j] = __builtin_amdgcn_mfma_f32_16x16x32_bf16(al[i], bh[j], acc[i][j], 0, 0, 0);
                acc[i][j] = __builtin_amdgcn_mfma_f32_16x16x32_bf16(ah[i], bl[j], acc[i][j], 0, 0, 0);
            }
        __syncthreads();
    }

    // epilogue: C/D layout col=lane&15, row=(lane>>4)*4+reg
#pragma unroll
    for (int i = 0; i < 4; ++i) {
        const size_t row0 = (size_t)by * 128 + wm * 64 + i * 16 + fq * 4;
#pragma unroll
        for (int j = 0; j < 4; ++j) {
            const int col = bx * 128 + wn * 64 + j * 16 + fr;
            const float bv = bias[col];
            float* cp = C + row0 * (size_t)ldc + col;
#pragma unroll
            for (int r = 0; r < 4; ++r)
                cp[(size_t)r * ldc] = acc[i][j][r] + bv;
        }
    }
}

// ---------------------------------------------------------------------------
// Partial kv/ksum per (T-chunk, bh): 8 x 128 = 1024 blocks.
// ---------------------------------------------------------------------------
__global__ __launch_bounds__(256) void kv_part_kernel(
    const float* __restrict__ qkv, const int* __restrict__ attn,
    float* __restrict__ kvpart, float* __restrict__ kspart)
{
    __shared__ float ks[32][64];
    __shared__ float vs[32][64];

    const int chunk = blockIdx.x;       // 0..7
    const int bh = blockIdx.y;          // 0..127
    const int b = bh >> 4;
    const int h = bh & 15;
    const int tid = threadIdx.x;
    const int tx = tid & 15;
    const int ty = tid >> 4;
    const int l_t = tid >> 4;
    const int l_d = (tid & 15) << 2;

    const float* kb = qkv + (size_t)b * Tdim * 3072 + 1024 + h * 64;
    const float* vb = qkv + (size_t)b * Tdim * 3072 + 2048 + h * 64;
    const int* am = attn + b * Tdim;

    float acc[4][4];
#pragma unroll
    for (int i = 0; i < 4; ++i)
#pragma unroll
        for (int j = 0; j < 4; ++j) acc[i][j] = 0.f;
    float ksl = 0.f;

    for (int t0 = chunk * 256; t0 < (chunk + 1) * 256; t0 += 32) {
        __syncthreads();
#pragma unroll
        for (int rr = 0; rr < 2; ++rr) {
            const int t = l_t + rr * 16;
            const int gt = t0 + t;
            const float m = (am[gt] > 0) ? 1.f : 0.f;
            const float4 k4 = *(const float4*)(kb + (size_t)gt * 3072 + l_d);
            const float4 v4 = *(const float4*)(vb + (size_t)gt * 3072 + l_d);
            float4 kp, vp;
            kp.x = phi_f(k4.x) * m; kp.y = phi_f(k4.y) * m;
            kp.z = phi_f(k4.z) * m; kp.w = phi_f(k4.w) * m;
            vp.x = v4.x * m; vp.y = v4.y * m; vp.z = v4.z * m; vp.w = v4.w * m;
            *(float4*)&ks[t][l_d] = kp;
            *(float4*)&vs[t][l_d] = vp;
        }
        __syncthreads();
#pragma unroll
        for (int t = 0; t < 32; ++t) {
            float kr[4], vr[4];
            *(float4*)kr = *(const float4*)&ks[t][ty * 4];
            *(float4*)vr = *(const float4*)&vs[t][tx * 4];
#pragma unroll
            for (int i = 0; i < 4; ++i)
#pragma unroll
                for (int j = 0; j < 4; ++j)
                    acc[i][j] = fmaf(kr[i], vr[j], acc[i][j]);
        }
        if (tid < 64) {
#pragma unroll
            for (int t = 0; t < 32; ++t) ksl += ks[t][tid];
        }
    }

    float* ko = kvpart + ((size_t)bh * 8 + chunk) * 4096;
#pragma unroll
    for (int i = 0; i < 4; ++i) {
        float4 o;
        o.x = acc[i][0]; o.y = acc[i][1]; o.z = acc[i][2]; o.w = acc[i][3];
        *(float4*)(ko + (ty * 4 + i) * 64 + tx * 4) = o;
    }
    if (tid < 64) kspart[((size_t)bh * 8 + chunk) * 64 + tid] = ksl;
}

__global__ __launch_bounds__(256) void kv_reduce_kernel(
    const float* __restrict__ kvpart, const float* __restrict__ kspart,
    float* __restrict__ kv, float* __restrict__ ksum)
{
    const int bh = blockIdx.x;
    const int tid = threadIdx.x;
    const float4* p = (const float4*)(kvpart + (size_t)bh * 8 * 4096);
    float4 s0 = {0,0,0,0}, s1 = {0,0,0,0}, s2 = {0,0,0,0}, s3 = {0,0,0,0};
#pragma unroll
    for (int c = 0; c < 8; ++c) {
        const int base = c * 1024;
        float4 a = p[base + tid], b = p[base + 256 + tid],
               cc = p[base + 512 + tid], d = p[base + 768 + tid];
        s0.x += a.x; s0.y += a.y; s0.z += a.z; s0.w += a.w;
        s1.x += b.x; s1.y += b.y; s1.z += b.z; s1.w += b.w;
        s2.x += cc.x; s2.y += cc.y; s2.z += cc.z; s2.w += cc.w;
        s3.x += d.x; s3.y += d.y; s3.z += d.z; s3.w += d.w;
    }
    float4* o = (float4*)(kv + (size_t)bh * 4096);
    o[tid] = s0; o[256 + tid] = s1; o[512 + tid] = s2; o[768 + tid] = s3;
    if (tid < 64) {
        float ss = 0.f;
#pragma unroll
        for (int c = 0; c < 8; ++c) ss += kspart[((size_t)bh * 8 + c) * 64 + tid];
        ksum[bh * 64 + tid] = ss;
    }
}

// ---------------------------------------------------------------------------
// y[t][f] = (phi(q[t])·kv[:,f]) / max(phi(q[t])·ksum, 1e-8).
// Writes y split hi/lo bf16 IN PLACE over this head's own q slot of qkv:
// per row, head hh's 64 fp32 (256 B) become y_hi[64] ++ y_lo[64] bf16.
// ---------------------------------------------------------------------------
__global__ __launch_bounds__(256) void attn_y_kernel(
    float* __restrict__ qkv, const float* __restrict__ kvin,
    const float* __restrict__ ksumin)
{
    __shared__ float qs[64][65];
    __shared__ float kvs[64][64];
    __shared__ float dinv[64];
    __shared__ float ksums[64];

    const int bh = blockIdx.y;
    const int b = bh >> 4;
    const int hh = bh & 15;
    const int t0 = blockIdx.x * 64;
    const int tid = threadIdx.x;
    const int tx = tid & 15;
    const int ty = tid >> 4;

    const float4* kvg = (const float4*)(kvin + (size_t)bh * 4096);
#pragma unroll
    for (int i = 0; i < 4; ++i)
        ((float4*)kvs)[tid + i * 256] = kvg[tid + i * 256];
    if (tid < 64) ksums[tid] = ksumin[bh * 64 + tid];

    float* qb = qkv + ((size_t)(b * Tdim + t0)) * 3072 + hh * 64;
#pragma unroll
    for (int rr = 0; rr < 4; ++rr) {
        const int t = (tid >> 4) + rr * 16;
        const int dd = (tid & 15) << 2;
        const float4 q4 = *(const float4*)(qb + (size_t)t * 3072 + dd);
        qs[t][dd + 0] = phi_f(q4.x);
        qs[t][dd + 1] = phi_f(q4.y);
        qs[t][dd + 2] = phi_f(q4.z);
        qs[t][dd + 3] = phi_f(q4.w);
    }
    __syncthreads();

    if (tid < 64) {
        float s = 0.f;
#pragma unroll
        for (int d = 0; d < 64; ++d) s = fmaf(qs[tid][d], ksums[d], s);
        dinv[tid] = 1.f / fmaxf(s, 1e-8f);
    }
    __syncthreads();

    float acc[4][4];
#pragma unroll
    for (int i = 0; i < 4; ++i)
#pragma unroll
        for (int j = 0; j < 4; ++j) acc[i][j] = 0.f;

#pragma unroll 4
    for (int d = 0; d < 64; ++d) {
        float qr[4];
        qr[0] = qs[ty * 4 + 0][d];
        qr[1] = qs[ty * 4 + 1][d];
        qr[2] = qs[ty * 4 + 2][d];
        qr[3] = qs[ty * 4 + 3][d];
        const float4 kr = *(const float4*)&kvs[d][tx * 4];
#pragma unroll
        for (int i = 0; i < 4; ++i) {
            acc[i][0] = fmaf(qr[i], kr.x, acc[i][0]);
            acc[i][1] = fmaf(qr[i], kr.y, acc[i][1]);
            acc[i][2] = fmaf(qr[i], kr.z, acc[i][2]);
            acc[i][3] = fmaf(qr[i], kr.w, acc[i][3]);
        }
    }

    // head-packed in-place write: row stride 6144 shorts (= 3072 fp32)
    short* qout = (short*)qkv + ((size_t)(b * Tdim + t0)) * 6144 + hh * 128;
#pragma unroll
    for (int i = 0; i < 4; ++i) {
        const float di = dinv[ty * 4 + i];
        short4v hv, lv;
#pragma unroll
        for (int j = 0; j < 4; ++j) {
            const float val = acc[i][j] * di;
            const short h = f2bf(val);
            hv[j] = h;
            lv[j] = f2bf(val - bf2f(h));
        }
        short* rp = qout + (size_t)(ty * 4 + i) * 6144;
        *(short4v*)(rp + tx * 4) = hv;        // hi plane [0..63]
        *(short4v*)(rp + 64 + tx * 4) = lv;   // lo plane [64..127]
    }
}

// ---------------------------------------------------------------------------
extern "C" void kernel_launch(void* const* d_in, const int* in_sizes, int n_in,
                              void* d_out, int out_size, void* d_ws, size_t ws_size,
                              hipStream_t stream)
{
    const float* x      = (const float*)d_in[0];
    const int*   attn   = (const int*)  d_in[1];
    const float* w_attn = (const float*)d_in[2];
    const float* b_attn = (const float*)d_in[3];
    const float* w_proj = (const float*)d_in[4];
    const float* b_proj = (const float*)d_in[5];
    float* out = (float*)d_out;

    // ---- workspace (~210.3 MiB) ----
    char* ws = (char*)d_ws;
    size_t off = 0;
    auto alloc = [&](size_t bytes) { void* p = ws + off; off = (off + bytes + 255) & ~(size_t)255; return p; };
    float* qkv   = (float*)alloc((size_t)16384 * 3072 * 4);   // 192 MiB
    short* waThi = (short*)alloc((size_t)3072 * 1024 * 2);    // 6 MiB
    short* waTlo = (short*)alloc((size_t)3072 * 1024 * 2);    // 6 MiB
    short* wpThi = (short*)alloc((size_t)1024 * 1024 * 2);    // 2 MiB
    short* wpTlo = (short*)alloc((size_t)1024 * 1024 * 2);    // 2 MiB
    float* kvb   = (float*)alloc((size_t)128 * 4096 * 4);     // 2 MiB
    float* ksum  = (float*)alloc((size_t)128 * 64 * 4);       // 32 KiB

    // ---- d_out doubles as scratch before GEMM2 rewrites it ----
    short* xhi = (short*)d_out;                               // 32 MiB
    short* xlo = xhi + (size_t)16384 * 1024;                  // 32 MiB
    float* kvpart = (float*)d_out;                            // 16 MiB (after GEMM1)
    float* kspart = (float*)((char*)d_out + (size_t)128 * 8 * 4096 * 4); // 256 KiB

    // 1) split x -> bf16 hi/lo (into d_out)
    split_kernel<<<16384, 256, 0, stream>>>(x, xhi, xlo, 4194304);
    // 2) transpose+split weights (into ws)
    split_transpose_kernel<<<dim3(96, 32), 256, 0, stream>>>(w_attn, 1024, 3072, waThi, waTlo);
    split_transpose_kernel<<<dim3(32, 32), 256, 0, stream>>>(w_proj, 1024, 1024, wpThi, wpTlo);
    // 3) qkv = x @ w_attn + b_attn  (M=16384,N=3072,K=1024)
    gemm3_kernel<0><<<dim3(24, 128), 256, 0, stream>>>(xhi, xlo, 1024, waThi, waTlo, b_attn, qkv, 1024, 3072);
    // 4) kv partials (into d_out) + reduce (into ws)
    kv_part_kernel<<<dim3(8, 128), 256, 0, stream>>>(qkv, attn, kvpart, kspart);
    kv_reduce_kernel<<<128, 256, 0, stream>>>(kvpart, kspart, kvb, ksum);
    // 5) y -> split bf16, head-packed in place over qkv's q slice
    attn_y_kernel<<<dim3(32, 128), 256, 0, stream>>>(qkv, kvb, ksum);
    // 6) out = y @ w_proj + b_proj  (M=16384,N=1024,K=1024); A head-packed in qkv
    gemm3_kernel<1><<<dim3(8, 128), 256, 0, stream>>>((const short*)qkv, (const short*)qkv, 6144,
                                                      wpThi, wpTlo, b_proj, out, 1024, 1024);
}

// Round 5
// 660.881 us; speedup vs baseline: 1.1561x; 1.1561x over previous
//
#include <hip/hip_runtime.h>

// (B,T,C,H) = (8,2048,1024,16), D=64
#define Tdim 2048

typedef __attribute__((ext_vector_type(8))) short bf16x8;
typedef __attribute__((ext_vector_type(4))) float f32x4;
typedef __attribute__((ext_vector_type(4))) short short4v;

#define GLOBAL_U32(p) ((const __attribute__((address_space(1))) unsigned int*)(p))
#define LDS_U32(p)    ((__attribute__((address_space(3))) unsigned int*)(p))

__device__ __forceinline__ float phi_f(float x) {
    return x > 0.f ? (x + 1.f) : __expf(x);
}
// round-to-nearest-even fp32 -> bf16 (finite inputs only)
__device__ __forceinline__ short f2bf(float f) {
    unsigned u = __float_as_uint(f);
    u += 0x7fffu + ((u >> 16) & 1u);
    return (short)(u >> 16);
}
__device__ __forceinline__ float bf2f(short h) {
    return __uint_as_float(((unsigned)(unsigned short)h) << 16);
}

// ===========================================================================
// TILED layout: matrix [R x K] bf16 stored as tiles of 16 rows x 32 k.
// Tile (rt, kt) at ((rt*(K/32))+kt)*512 shorts; slot L (0..63) holds
// row rt*16+(L&15), k = kt*32+(L>>4)*8 .. +8.  One wave staging instr = 1 KB
// contiguous; fragment read = tile_base + lane*16B (conflict-free identity).
// ===========================================================================

// ---------------------------------------------------------------------------
// x [16384 x 1024] fp32 -> tiled split hi/lo. Block: 16 rows x 128 cols.
// ---------------------------------------------------------------------------
__global__ __launch_bounds__(256) void split_tile_kernel(
    const float* __restrict__ X, short* __restrict__ Hi, short* __restrict__ Lo)
{
    const int rt = blockIdx.x;          // row-tile 0..1023
    const int cb = blockIdx.y;          // col-block 0..7 (128 cols)
    const int t = threadIdx.x;
    const int rl = t >> 4;              // row in tile 0..15
    const int cc = t & 15;              // col-chunk (8 cols) 0..15

    const float* xp = X + ((size_t)rt * 16 + rl) * 1024 + cb * 128 + cc * 8;
    const float4 a = *(const float4*)xp;
    const float4 b = *(const float4*)(xp + 4);
    float v[8] = {a.x, a.y, a.z, a.w, b.x, b.y, b.z, b.w};
    bf16x8 h, l;
#pragma unroll
    for (int j = 0; j < 8; ++j) {
        const short hh = f2bf(v[j]);
        h[j] = hh;
        l[j] = f2bf(v[j] - bf2f(hh));
    }
    const int kt = cb * 4 + (cc >> 2);
    const int slot = ((cc & 3) << 4) | rl;
    const size_t off = ((size_t)rt * 32 + kt) * 512 + slot * 8;
    *(bf16x8*)(Hi + off) = h;
    *(bf16x8*)(Lo + off) = l;
}

// ---------------------------------------------------------------------------
// W [1024 x N] fp32 -> W^T [N x 1024] tiled split hi/lo. One wave per tile.
// nkt = 1024/32 = 32 (hardcoded).
// ---------------------------------------------------------------------------
__global__ __launch_bounds__(256) void w_tile_kernel(
    const float* __restrict__ W, int N,
    short* __restrict__ Thi, short* __restrict__ Tlo)
{
    const int tile = blockIdx.x * 4 + (threadIdx.x >> 6);
    const int nt = tile >> 5;           // n-tile
    const int kt = tile & 31;           // k-tile
    const int lane = threadIdx.x & 63;
    const int n = nt * 16 + (lane & 15);
    const int k = kt * 32 + (lane >> 4) * 8;
    const float* wp = W + (size_t)k * N + n;
    bf16x8 h, l;
#pragma unroll
    for (int j = 0; j < 8; ++j) {
        const float v = wp[(size_t)j * N];
        const short hh = f2bf(v);
        h[j] = hh;
        l[j] = f2bf(v - bf2f(hh));
    }
    const size_t off = (size_t)tile * 512 + lane * 8;
    *(bf16x8*)(Thi + off) = h;
    *(bf16x8*)(Tlo + off) = l;
}

// ---------------------------------------------------------------------------
// bf16x3 split-precision GEMM: C = (Ahi+Alo)[M,K] * (Bhi+Blo)^T[N,K] + bias
// (drops lo*lo). 128x128 tile, BK=32, 4 waves x (4x4 of 16x16x32 MFMA).
// B always TILED.  AMODE 0: A TILED.  AMODE 1: A head-packed in qkv (row
// stride lda shorts; k -> slot (k>>6)*128 + (k&63), lo at +64), staged with
// the round-3 monotone lane map (row=lane>>2, chunk=lane&3).
// K = 1024 (nkt = 32) for both uses.
// ---------------------------------------------------------------------------
template<int AMODE>
__global__ __launch_bounds__(256) void gemm3_kernel(
    const short* __restrict__ Ahi, const short* __restrict__ Alo, int lda,
    const short* __restrict__ BThi, const short* __restrict__ BTlo,
    const float* __restrict__ bias, float* __restrict__ C,
    int K, int ldc)
{
    __shared__ short smem[16384];   // 4 arrays x 8 tiles x 512 shorts = 32 KiB
    const int tid = threadIdx.x;
    const int lane = tid & 63;
    const int wid = tid >> 6;       // wave 0..3
    const int bx = blockIdx.x, by = blockIdx.y;
    const int wm = wid >> 1, wn = wid & 1;

    const size_t tilestep = (size_t)(K >> 5) * 512;   // shorts per row-tile

    // staging: wave w owns LDS array w (0:Ahi 1:Alo 2:BThi 3:BTlo)
    const short* gptr;
    if (wid < 2) {
        const short* gb = (wid == 0) ? Ahi : Alo;
        if (AMODE == 0)
            gptr = gb + (size_t)(by * 8) * tilestep + lane * 8;
        else
            gptr = gb + ((size_t)by * 128 + (lane >> 2)) * (size_t)lda + (lane & 3) * 8;
    } else {
        const short* gb = (wid == 2) ? BThi : BTlo;
        gptr = gb + (size_t)(bx * 8) * tilestep + lane * 8;
    }
    short* lbase = smem + wid * 4096;   // wave-uniform LDS base (shorts)

    f32x4 acc[4][4];
#pragma unroll
    for (int i = 0; i < 4; ++i)
#pragma unroll
        for (int j = 0; j < 4; ++j) acc[i][j] = (f32x4){0.f, 0.f, 0.f, 0.f};

    const int fr = lane & 15, fq = lane >> 4;
    // intra-tile fragment offset (shorts)
    const int aoff = (AMODE == 0) ? lane * 8 : (fr * 32 + fq * 8);
    const int boff = lane * 8;

    for (int k0 = 0; k0 < K; k0 += 32) {
        if (AMODE == 0 || wid >= 2) {
            const short* g = gptr + (size_t)(k0 >> 5) * 512;
#pragma unroll
            for (int c = 0; c < 8; ++c)
                __builtin_amdgcn_global_load_lds(
                    GLOBAL_U32(g + (size_t)c * tilestep),
                    LDS_U32(lbase + c * 512), 16, 0, 0);
        } else {
            const int koff = ((k0 >> 6) << 7) + (k0 & 63) + (wid == 1 ? 64 : 0);
#pragma unroll
            for (int c = 0; c < 8; ++c)
                __builtin_amdgcn_global_load_lds(
                    GLOBAL_U32(gptr + (size_t)(c * 16) * lda + koff),
                    LDS_U32(lbase + c * 512), 16, 0, 0);
        }
        __syncthreads();

        bf16x8 ah[4], al[4], bh[4], bl[4];
#pragma unroll
        for (int i = 0; i < 4; ++i) {
            ah[i] = *(const bf16x8*)(smem + (wm * 4 + i) * 512 + aoff);
            al[i] = *(const bf16x8*)(smem + 4096 + (wm * 4 + i) * 512 + aoff);
            bh[i] = *(const bf16x8*)(smem + 8192 + (wn * 4 + i) * 512 + boff);
            bl[i] = *(const bf16x8*)(smem + 12288 + (wn * 4 + i) * 512 + boff);
        }
#pragma unroll
        for (int i = 0; i < 4; ++i)
#pragma unroll
            for (int j = 0; j < 4; ++j) {
                acc[i][j] = __builtin_amdgcn_mfma_f32_16x16x32_bf16(ah[i], bh[j], acc[i][j], 0, 0, 0);
                acc[i][j] = __builtin_amdgcn_mfma_f32_16x16x32_bf16(al[i], bh[j], acc[i][j], 0, 0, 0);
                acc[i][j] = __builtin_amdgcn_mfma_f32_16x16x32_bf16(ah[i], bl[j], acc[i][j], 0, 0, 0);
            }
        __syncthreads();
    }

    // epilogue: C/D layout col=lane&15, row=(lane>>4)*4+reg
#pragma unroll
    for (int i = 0; i < 4; ++i) {
        const size_t row0 = (size_t)by * 128 + wm * 64 + i * 16 + fq * 4;
#pragma unroll
        for (int j = 0; j < 4; ++j) {
            const int col = bx * 128 + wn * 64 + j * 16 + fr;
            const float bv = bias[col];
            float* cp = C + row0 * (size_t)ldc + col;
#pragma unroll
            for (int r = 0; r < 4; ++r)
                cp[(size_t)r * ldc] = acc[i][j][r] + bv;
        }
    }
}

// ---------------------------------------------------------------------------
// Partial kv/ksum per (T-chunk, bh): 8 x 128 = 1024 blocks.
// ---------------------------------------------------------------------------
__global__ __launch_bounds__(256) void kv_part_kernel(
    const float* __restrict__ qkv, const int* __restrict__ attn,
    float* __restrict__ kvpart, float* __restrict__ kspart)
{
    __shared__ float ks[32][64];
    __shared__ float vs[32][64];

    const int chunk = blockIdx.x;       // 0..7
    const int bh = blockIdx.y;          // 0..127
    const int b = bh >> 4;
    const int h = bh & 15;
    const int tid = threadIdx.x;
    const int tx = tid & 15;
    const int ty = tid >> 4;
    const int l_t = tid >> 4;
    const int l_d = (tid & 15) << 2;

    const float* kb = qkv + (size_t)b * Tdim * 3072 + 1024 + h * 64;
    const float* vb = qkv + (size_t)b * Tdim * 3072 + 2048 + h * 64;
    const int* am = attn + b * Tdim;

    float acc[4][4];
#pragma unroll
    for (int i = 0; i < 4; ++i)
#pragma unroll
        for (int j = 0; j < 4; ++j) acc[i][j] = 0.f;
    float ksl = 0.f;

    for (int t0 = chunk * 256; t0 < (chunk + 1) * 256; t0 += 32) {
        __syncthreads();
#pragma unroll
        for (int rr = 0; rr < 2; ++rr) {
            const int t = l_t + rr * 16;
            const int gt = t0 + t;
            const float m = (am[gt] > 0) ? 1.f : 0.f;
            const float4 k4 = *(const float4*)(kb + (size_t)gt * 3072 + l_d);
            const float4 v4 = *(const float4*)(vb + (size_t)gt * 3072 + l_d);
            float4 kp, vp;
            kp.x = phi_f(k4.x) * m; kp.y = phi_f(k4.y) * m;
            kp.z = phi_f(k4.z) * m; kp.w = phi_f(k4.w) * m;
            vp.x = v4.x * m; vp.y = v4.y * m; vp.z = v4.z * m; vp.w = v4.w * m;
            *(float4*)&ks[t][l_d] = kp;
            *(float4*)&vs[t][l_d] = vp;
        }
        __syncthreads();
#pragma unroll
        for (int t = 0; t < 32; ++t) {
            float kr[4], vr[4];
            *(float4*)kr = *(const float4*)&ks[t][ty * 4];
            *(float4*)vr = *(const float4*)&vs[t][tx * 4];
#pragma unroll
            for (int i = 0; i < 4; ++i)
#pragma unroll
                for (int j = 0; j < 4; ++j)
                    acc[i][j] = fmaf(kr[i], vr[j], acc[i][j]);
        }
        if (tid < 64) {
#pragma unroll
            for (int t = 0; t < 32; ++t) ksl += ks[t][tid];
        }
    }

    float* ko = kvpart + ((size_t)bh * 8 + chunk) * 4096;
#pragma unroll
    for (int i = 0; i < 4; ++i) {
        float4 o;
        o.x = acc[i][0]; o.y = acc[i][1]; o.z = acc[i][2]; o.w = acc[i][3];
        *(float4*)(ko + (ty * 4 + i) * 64 + tx * 4) = o;
    }
    if (tid < 64) kspart[((size_t)bh * 8 + chunk) * 64 + tid] = ksl;
}

__global__ __launch_bounds__(256) void kv_reduce_kernel(
    const float* __restrict__ kvpart, const float* __restrict__ kspart,
    float* __restrict__ kv, float* __restrict__ ksum)
{
    const int bh = blockIdx.x;
    const int tid = threadIdx.x;
    const float4* p = (const float4*)(kvpart + (size_t)bh * 8 * 4096);
    float4 s0 = {0,0,0,0}, s1 = {0,0,0,0}, s2 = {0,0,0,0}, s3 = {0,0,0,0};
#pragma unroll
    for (int c = 0; c < 8; ++c) {
        const int base = c * 1024;
        float4 a = p[base + tid], b = p[base + 256 + tid],
               cc = p[base + 512 + tid], d = p[base + 768 + tid];
        s0.x += a.x; s0.y += a.y; s0.z += a.z; s0.w += a.w;
        s1.x += b.x; s1.y += b.y; s1.z += b.z; s1.w += b.w;
        s2.x += cc.x; s2.y += cc.y; s2.z += cc.z; s2.w += cc.w;
        s3.x += d.x; s3.y += d.y; s3.z += d.z; s3.w += d.w;
    }
    float4* o = (float4*)(kv + (size_t)bh * 4096);
    o[tid] = s0; o[256 + tid] = s1; o[512 + tid] = s2; o[768 + tid] = s3;
    if (tid < 64) {
        float ss = 0.f;
#pragma unroll
        for (int c = 0; c < 8; ++c) ss += kspart[((size_t)bh * 8 + c) * 64 + tid];
        ksum[bh * 64 + tid] = ss;
    }
}

// ---------------------------------------------------------------------------
// y[t][f] = (phi(q[t])·kv[:,f]) / max(phi(q[t])·ksum, 1e-8).
// Writes y split hi/lo bf16 IN PLACE over this head's own q slot of qkv:
// per row, head hh's 64 fp32 (256 B) become y_hi[64] ++ y_lo[64] bf16.
// ---------------------------------------------------------------------------
__global__ __launch_bounds__(256) void attn_y_kernel(
    float* __restrict__ qkv, const float* __restrict__ kvin,
    const float* __restrict__ ksumin)
{
    __shared__ float qs[64][65];
    __shared__ float kvs[64][64];
    __shared__ float dinv[64];
    __shared__ float ksums[64];

    const int bh = blockIdx.y;
    const int b = bh >> 4;
    const int hh = bh & 15;
    const int t0 = blockIdx.x * 64;
    const int tid = threadIdx.x;
    const int tx = tid & 15;
    const int ty = tid >> 4;

    const float4* kvg = (const float4*)(kvin + (size_t)bh * 4096);
#pragma unroll
    for (int i = 0; i < 4; ++i)
        ((float4*)kvs)[tid + i * 256] = kvg[tid + i * 256];
    if (tid < 64) ksums[tid] = ksumin[bh * 64 + tid];

    float* qb = qkv + ((size_t)(b * Tdim + t0)) * 3072 + hh * 64;
#pragma unroll
    for (int rr = 0; rr < 4; ++rr) {
        const int t = (tid >> 4) + rr * 16;
        const int dd = (tid & 15) << 2;
        const float4 q4 = *(const float4*)(qb + (size_t)t * 3072 + dd);
        qs[t][dd + 0] = phi_f(q4.x);
        qs[t][dd + 1] = phi_f(q4.y);
        qs[t][dd + 2] = phi_f(q4.z);
        qs[t][dd + 3] = phi_f(q4.w);
    }
    __syncthreads();

    if (tid < 64) {
        float s = 0.f;
#pragma unroll
        for (int d = 0; d < 64; ++d) s = fmaf(qs[tid][d], ksums[d], s);
        dinv[tid] = 1.f / fmaxf(s, 1e-8f);
    }
    __syncthreads();

    float acc[4][4];
#pragma unroll
    for (int i = 0; i < 4; ++i)
#pragma unroll
        for (int j = 0; j < 4; ++j) acc[i][j] = 0.f;

#pragma unroll 4
    for (int d = 0; d < 64; ++d) {
        float qr[4];
        qr[0] = qs[ty * 4 + 0][d];
        qr[1] = qs[ty * 4 + 1][d];
        qr[2] = qs[ty * 4 + 2][d];
        qr[3] = qs[ty * 4 + 3][d];
        const float4 kr = *(const float4*)&kvs[d][tx * 4];
#pragma unroll
        for (int i = 0; i < 4; ++i) {
            acc[i][0] = fmaf(qr[i], kr.x, acc[i][0]);
            acc[i][1] = fmaf(qr[i], kr.y, acc[i][1]);
            acc[i][2] = fmaf(qr[i], kr.z, acc[i][2]);
            acc[i][3] = fmaf(qr[i], kr.w, acc[i][3]);
        }
    }

    // head-packed in-place write: row stride 6144 shorts (= 3072 fp32)
    short* qout = (short*)qkv + ((size_t)(b * Tdim + t0)) * 6144 + hh * 128;
#pragma unroll
    for (int i = 0; i < 4; ++i) {
        const float di = dinv[ty * 4 + i];
        short4v hv, lv;
#pragma unroll
        for (int j = 0; j < 4; ++j) {
            const float val = acc[i][j] * di;
            const short h = f2bf(val);
            hv[j] = h;
            lv[j] = f2bf(val - bf2f(h));
        }
        short* rp = qout + (size_t)(ty * 4 + i) * 6144;
        *(short4v*)(rp + tx * 4) = hv;        // hi plane [0..63]
        *(short4v*)(rp + 64 + tx * 4) = lv;   // lo plane [64..127]
    }
}

// ---------------------------------------------------------------------------
extern "C" void kernel_launch(void* const* d_in, const int* in_sizes, int n_in,
                              void* d_out, int out_size, void* d_ws, size_t ws_size,
                              hipStream_t stream)
{
    const float* x      = (const float*)d_in[0];
    const int*   attn   = (const int*)  d_in[1];
    const float* w_attn = (const float*)d_in[2];
    const float* b_attn = (const float*)d_in[3];
    const float* w_proj = (const float*)d_in[4];
    const float* b_proj = (const float*)d_in[5];
    float* out = (float*)d_out;

    // ---- workspace (~210.3 MiB) ----
    char* ws = (char*)d_ws;
    size_t off = 0;
    auto alloc = [&](size_t bytes) { void* p = ws + off; off = (off + bytes + 255) & ~(size_t)255; return p; };
    float* qkv   = (float*)alloc((size_t)16384 * 3072 * 4);   // 192 MiB
    short* waThi = (short*)alloc((size_t)3072 * 1024 * 2);    // 6 MiB (tiled)
    short* waTlo = (short*)alloc((size_t)3072 * 1024 * 2);    // 6 MiB
    short* wpThi = (short*)alloc((size_t)1024 * 1024 * 2);    // 2 MiB
    short* wpTlo = (short*)alloc((size_t)1024 * 1024 * 2);    // 2 MiB
    float* kvb   = (float*)alloc((size_t)128 * 4096 * 4);     // 2 MiB
    float* ksum  = (float*)alloc((size_t)128 * 64 * 4);       // 32 KiB

    // ---- d_out doubles as scratch before GEMM2 rewrites it ----
    short* xhi = (short*)d_out;                               // 32 MiB (tiled)
    short* xlo = xhi + (size_t)16384 * 1024;                  // 32 MiB
    float* kvpart = (float*)d_out;                            // 16 MiB (after GEMM1)
    float* kspart = (float*)((char*)d_out + (size_t)128 * 8 * 4096 * 4); // 256 KiB

    // 1) split x -> tiled bf16 hi/lo (into d_out)
    split_tile_kernel<<<dim3(1024, 8), 256, 0, stream>>>(x, xhi, xlo);
    // 2) transpose+split weights into tiled layout (into ws)
    w_tile_kernel<<<1536, 256, 0, stream>>>(w_attn, 3072, waThi, waTlo);  // 6144 tiles
    w_tile_kernel<<<512, 256, 0, stream>>>(w_proj, 1024, wpThi, wpTlo);   // 2048 tiles
    // 3) qkv = x @ w_attn + b_attn  (M=16384,N=3072,K=1024), A+B tiled
    gemm3_kernel<0><<<dim3(24, 128), 256, 0, stream>>>(xhi, xlo, 0, waThi, waTlo, b_attn, qkv, 1024, 3072);
    // 4) kv partials (into d_out) + reduce (into ws)
    kv_part_kernel<<<dim3(8, 128), 256, 0, stream>>>(qkv, attn, kvpart, kspart);
    kv_reduce_kernel<<<128, 256, 0, stream>>>(kvpart, kspart, kvb, ksum);
    // 5) y -> split bf16, head-packed in place over qkv's q slice
    attn_y_kernel<<<dim3(32, 128), 256, 0, stream>>>(qkv, kvb, ksum);
    // 6) out = y @ w_proj + b_proj  (M=16384,N=1024,K=1024); A head-packed, B tiled
    gemm3_kernel<1><<<dim3(8, 128), 256, 0, stream>>>((const short*)qkv, (const short*)qkv, 6144,
                                                      wpThi, wpTlo, b_proj, out, 1024, 1024);
}